// Round 1
// baseline (480.155 us; speedup 1.0000x reference)
//
#include <hip/hip_runtime.h>
#include <hip/hip_bf16.h>

// ACM-GCN style graph conv:
//   h_l = x@W_low ; h_h = x@W_high ; h_m = relu(x@W_mlp)
//   out_low  = relu(spmm(A_low,  h_l))
//   out_high = relu(spmm(A_high, h_h))
//   feats = [out_low@a_low, out_high@a_high, h_m@a_mlp]  (per node, 3 scalars)
//   att = softmax(sigmoid(feats) @ att3 / 3)
//   out = 3*(att0*out_low + att1*out_high + att2*h_m)

// ---------------------------------------------------------------------------
// K1: three skinny GEMMs [N,64]@[64,64]. One wave per block so row addresses
// are wave-uniform -> scalar (s_load) x-row loads; W column lives in 64 VGPRs.
// 4-row blocking for FMA ILP. n must be divisible by 4 (50000 is).
// ---------------------------------------------------------------------------
__global__ __launch_bounds__(64)
void gemm3_kernel(const float* __restrict__ x,
                  const float* __restrict__ Wl, const float* __restrict__ Wh,
                  const float* __restrict__ Wm,
                  float* __restrict__ hl, float* __restrict__ hh,
                  float* __restrict__ hm, int n)
{
    const int m = blockIdx.y;
    const float* __restrict__ W = (m == 0) ? Wl : (m == 1) ? Wh : Wm;
    float* __restrict__ H = (m == 0) ? hl : (m == 1) ? hh : hm;
    const int lane = threadIdx.x;  // 0..63 == output column

    // Preload my output column of W into registers (64 VGPRs).
    float wcol[64];
#pragma unroll
    for (int k = 0; k < 64; ++k) wcol[k] = W[k * 64 + lane];

    const int row0 = blockIdx.x * 64;
#pragma unroll 1
    for (int rr = 0; rr < 64; rr += 4) {
        const int r = row0 + rr;
        if (r >= n) break;  // n % 4 == 0 so groups are all-or-nothing
        const float* __restrict__ x0 = x + (size_t)r * 64;
        float a0 = 0.f, a1 = 0.f, a2 = 0.f, a3 = 0.f;
#pragma unroll
        for (int k = 0; k < 64; ++k) {
            const float w = wcol[k];
            a0 = fmaf(x0[k], w, a0);        // x0[k] is wave-uniform -> SGPR
            a1 = fmaf(x0[64 + k], w, a1);
            a2 = fmaf(x0[128 + k], w, a2);
            a3 = fmaf(x0[192 + k], w, a3);
        }
        if (m == 2) {  // out_mlp gets its relu here
            a0 = fmaxf(a0, 0.f); a1 = fmaxf(a1, 0.f);
            a2 = fmaxf(a2, 0.f); a3 = fmaxf(a3, 0.f);
        }
        H[(size_t)r * 64 + lane] = a0;
        H[(size_t)(r + 1) * 64 + lane] = a1;
        H[(size_t)(r + 2) * 64 + lane] = a2;
        H[(size_t)(r + 3) * 64 + lane] = a3;
    }
}

// ---------------------------------------------------------------------------
// K2: COO SpMM scatter: acc[row[e]][:] += val[e] * h[col[e]][:]
// One wave per block -> edge indices are scalar loads; lane = feature.
// ---------------------------------------------------------------------------
__global__ __launch_bounds__(64)
void spmm_kernel(const int* __restrict__ row, const int* __restrict__ col,
                 const float* __restrict__ val, const float* __restrict__ h,
                 float* __restrict__ acc, int E)
{
    const int lane = threadIdx.x;
    const int nb = gridDim.x;
#pragma unroll 1
    for (int e = blockIdx.x; e < E; e += nb) {
        const int r = row[e];
        const int c = col[e];
        const float v = val[e];
        const float hv = h[(size_t)c * 64 + lane];
        atomicAdd(&acc[(size_t)r * 64 + lane], v * hv);
    }
}

// ---------------------------------------------------------------------------
// K3: per-node attention fusion. One wave per node; lane = feature.
// ---------------------------------------------------------------------------
__global__ __launch_bounds__(256)
void finalize_kernel(const float* __restrict__ accL, const float* __restrict__ accH,
                     const float* __restrict__ hm,
                     const float* __restrict__ aL, const float* __restrict__ aH,
                     const float* __restrict__ aM, const float* __restrict__ att3,
                     float* __restrict__ out, int n)
{
    const int gtid = blockIdx.x * blockDim.x + threadIdx.x;
    const int node = gtid >> 6;
    const int lane = threadIdx.x & 63;
    if (node >= n) return;
    const size_t base = (size_t)node * 64 + lane;

    const float ol = fmaxf(accL[base], 0.f);   // relu(spmm_low)
    const float oh = fmaxf(accH[base], 0.f);   // relu(spmm_high)
    const float om = hm[base];                 // already relu'd

    float f0 = ol * aL[lane];
    float f1 = oh * aH[lane];
    float f2 = om * aM[lane];
#pragma unroll
    for (int msk = 1; msk < 64; msk <<= 1) {
        f0 += __shfl_xor(f0, msk, 64);
        f1 += __shfl_xor(f1, msk, 64);
        f2 += __shfl_xor(f2, msk, 64);
    }
    const float s0 = 1.f / (1.f + __expf(-f0));
    const float s1 = 1.f / (1.f + __expf(-f1));
    const float s2 = 1.f / (1.f + __expf(-f2));
    const float invT = 1.f / 3.f;
    // logits[c] = sum_r s_r * att3[r][c] ; att3 row-major [3][3]
    const float l0 = (s0 * att3[0] + s1 * att3[3] + s2 * att3[6]) * invT;
    const float l1 = (s0 * att3[1] + s1 * att3[4] + s2 * att3[7]) * invT;
    const float l2 = (s0 * att3[2] + s1 * att3[5] + s2 * att3[8]) * invT;
    const float mx = fmaxf(l0, fmaxf(l1, l2));
    const float e0 = __expf(l0 - mx);
    const float e1 = __expf(l1 - mx);
    const float e2 = __expf(l2 - mx);
    const float inv = 1.f / (e0 + e1 + e2);
    out[base] = 3.f * inv * (e0 * ol + e1 * oh + e2 * om);
}

extern "C" void kernel_launch(void* const* d_in, const int* in_sizes, int n_in,
                              void* d_out, int out_size, void* d_ws, size_t ws_size,
                              hipStream_t stream)
{
    const float* x        = (const float*)d_in[0];
    const int*   row_low  = (const int*)  d_in[1];
    const int*   col_low  = (const int*)  d_in[2];
    const float* val_low  = (const float*)d_in[3];
    const int*   row_high = (const int*)  d_in[4];
    const int*   col_high = (const int*)  d_in[5];
    const float* val_high = (const float*)d_in[6];
    const float* W_low    = (const float*)d_in[7];
    const float* W_high   = (const float*)d_in[8];
    const float* W_mlp    = (const float*)d_in[9];
    const float* a_low    = (const float*)d_in[10];
    const float* a_high   = (const float*)d_in[11];
    const float* a_mlp    = (const float*)d_in[12];
    const float* att3     = (const float*)d_in[13];
    float* out = (float*)d_out;

    const int N = in_sizes[0] / 64;   // 50000
    const int E = in_sizes[1];        // 800000
    const size_t NM = (size_t)N * 64;

    float* hl   = (float*)d_ws;
    float* hh   = hl + NM;
    float* hm   = hh + NM;
    float* accL = hm + NM;
    float* accH = accL + NM;

    // zero the scatter accumulators each call (harness poisons ws once)
    hipMemsetAsync(accL, 0, 2 * NM * sizeof(float), stream);

    dim3 g1((N + 63) / 64, 3);
    gemm3_kernel<<<g1, 64, 0, stream>>>(x, W_low, W_high, W_mlp, hl, hh, hm, N);

    spmm_kernel<<<8192, 64, 0, stream>>>(row_low, col_low, val_low, hl, accL, E);
    spmm_kernel<<<8192, 64, 0, stream>>>(row_high, col_high, val_high, hh, accH, E);

    finalize_kernel<<<(N * 64 + 255) / 256, 256, 0, stream>>>(
        accL, accH, hm, a_low, a_high, a_mlp, att3, out, N);
}

// Round 2
// 422.087 us; speedup vs baseline: 1.1376x; 1.1376x over previous
//
#include <hip/hip_runtime.h>
#include <hip/hip_bf16.h>

// ACM-GCN graph conv. R2: replace atomic scatter-SpMM (device-scope atomics
// write through past the non-coherent per-XCD L2 -> 200MB HBM writes, 178us
// per graph) with an on-device CSR build + row-parallel gather SpMM fused
// with the attention finalize.

#define NNODE 50000
#define NEDGE 800000

// ---------------------------------------------------------------------------
// K1: three skinny GEMMs [N,64]@[64,64]. One wave per block -> wave-uniform
// x-row loads (scalar path); W column in 64 VGPRs; 4-row FMA blocking.
// ---------------------------------------------------------------------------
__global__ __launch_bounds__(64)
void gemm3_kernel(const float* __restrict__ x,
                  const float* __restrict__ Wl, const float* __restrict__ Wh,
                  const float* __restrict__ Wm,
                  float* __restrict__ hl, float* __restrict__ hh,
                  float* __restrict__ hm, int n)
{
    const int m = blockIdx.y;
    const float* __restrict__ W = (m == 0) ? Wl : (m == 1) ? Wh : Wm;
    float* __restrict__ H = (m == 0) ? hl : (m == 1) ? hh : hm;
    const int lane = threadIdx.x;

    float wcol[64];
#pragma unroll
    for (int k = 0; k < 64; ++k) wcol[k] = W[k * 64 + lane];

    const int row0 = blockIdx.x * 64;
#pragma unroll 1
    for (int rr = 0; rr < 64; rr += 4) {
        const int r = row0 + rr;
        if (r >= n) break;
        const float* __restrict__ x0 = x + (size_t)r * 64;
        float a0 = 0.f, a1 = 0.f, a2 = 0.f, a3 = 0.f;
#pragma unroll
        for (int k = 0; k < 64; ++k) {
            const float w = wcol[k];
            a0 = fmaf(x0[k], w, a0);
            a1 = fmaf(x0[64 + k], w, a1);
            a2 = fmaf(x0[128 + k], w, a2);
            a3 = fmaf(x0[192 + k], w, a3);
        }
        if (m == 2) {
            a0 = fmaxf(a0, 0.f); a1 = fmaxf(a1, 0.f);
            a2 = fmaxf(a2, 0.f); a3 = fmaxf(a3, 0.f);
        }
        H[(size_t)r * 64 + lane] = a0;
        H[(size_t)(r + 1) * 64 + lane] = a1;
        H[(size_t)(r + 2) * 64 + lane] = a2;
        H[(size_t)(r + 3) * 64 + lane] = a3;
    }
}

// ---------------------------------------------------------------------------
// K2: histogram of destination rows for both graphs (cnt[g*N + r]++).
// ---------------------------------------------------------------------------
__global__ __launch_bounds__(256)
void hist_kernel(const int* __restrict__ row_low, const int* __restrict__ row_high,
                 int* __restrict__ cnt)
{
    const int stride = gridDim.x * blockDim.x;
    for (int t = blockIdx.x * blockDim.x + threadIdx.x; t < 2 * NEDGE; t += stride) {
        if (t < NEDGE) atomicAdd(cnt + row_low[t], 1);
        else           atomicAdd(cnt + NNODE + row_high[t - NEDGE], 1);
    }
}

// ---------------------------------------------------------------------------
// K3: exclusive scan of one graph's counters -> start[] and cursor[].
// One 1024-thread block per graph (blockIdx.x = graph).
// ---------------------------------------------------------------------------
__global__ __launch_bounds__(1024)
void scan_kernel(const int* __restrict__ cnt, int* __restrict__ startL,
                 int* __restrict__ startH, int* __restrict__ cursor)
{
    const int g = blockIdx.x;
    const int* __restrict__ c = cnt + g * NNODE;
    int* __restrict__ start = (g == 0) ? startL : startH;
    int* __restrict__ cur = cursor + g * NNODE;

    __shared__ int wsum[16];
    __shared__ int s_carry;
    const int t = threadIdx.x, wid = t >> 6, lane = t & 63;
    if (t == 0) s_carry = 0;
    __syncthreads();

    for (int base = 0; base < NNODE; base += 1024) {
        const int idx = base + t;
        const int v = (idx < NNODE) ? c[idx] : 0;
        // inclusive wave scan
        int x = v;
#pragma unroll
        for (int d = 1; d < 64; d <<= 1) {
            int y = __shfl_up(x, d, 64);
            if (lane >= d) x += y;
        }
        if (lane == 63) wsum[wid] = x;
        __syncthreads();
        if (wid == 0) {
            int s = (lane < 16) ? wsum[lane] : 0;
#pragma unroll
            for (int d = 1; d < 16; d <<= 1) {
                int y = __shfl_up(s, d, 64);
                if (lane >= d) s += y;
            }
            if (lane < 16) wsum[lane] = s;
        }
        __syncthreads();
        const int woff = (wid > 0) ? wsum[wid - 1] : 0;
        const int excl = s_carry + x + woff - v;
        if (idx < NNODE) { start[idx] = excl; cur[idx] = excl; }
        const int chunk_total = wsum[15];
        __syncthreads();
        if (t == 0) s_carry += chunk_total;
        __syncthreads();
    }
    if (t == 0) start[NNODE] = s_carry;  // == NEDGE
}

// ---------------------------------------------------------------------------
// K4: scatter edges into CSR order as packed {col_bits, val} float2.
// ---------------------------------------------------------------------------
__global__ __launch_bounds__(256)
void scatter_kernel(const int* __restrict__ row_low, const int* __restrict__ col_low,
                    const float* __restrict__ val_low,
                    const int* __restrict__ row_high, const int* __restrict__ col_high,
                    const float* __restrict__ val_high,
                    int* __restrict__ cursor,
                    float2* __restrict__ packedL, float2* __restrict__ packedH)
{
    const int stride = gridDim.x * blockDim.x;
    for (int t = blockIdx.x * blockDim.x + threadIdx.x; t < 2 * NEDGE; t += stride) {
        if (t < NEDGE) {
            const int r = row_low[t];
            const int pos = atomicAdd(cursor + r, 1);
            float2 p; p.x = __int_as_float(col_low[t]); p.y = val_low[t];
            packedL[pos] = p;
        } else {
            const int e = t - NEDGE;
            const int r = row_high[e];
            const int pos = atomicAdd(cursor + NNODE + r, 1);
            float2 p; p.x = __int_as_float(col_high[e]); p.y = val_high[e];
            packedH[pos] = p;
        }
    }
}

// ---------------------------------------------------------------------------
// K5: fused CSR-SpMM (both graphs) + relu + attention finalize.
// One wave per node; lane = feature. No atomics, register accumulation.
// ---------------------------------------------------------------------------
__global__ __launch_bounds__(256)
void spmm_finalize_kernel(const int* __restrict__ startL, const int* __restrict__ startH,
                          const float2* __restrict__ packedL, const float2* __restrict__ packedH,
                          const float* __restrict__ hl, const float* __restrict__ hh,
                          const float* __restrict__ hm,
                          const float* __restrict__ aL, const float* __restrict__ aH,
                          const float* __restrict__ aM, const float* __restrict__ att3,
                          float* __restrict__ out)
{
    const int wid = threadIdx.x >> 6;
    const int lane = threadIdx.x & 63;
    const int node = blockIdx.x * 4 + wid;
    if (node >= NNODE) return;

    float accL = 0.f, accH = 0.f;
    {
        const int s = startL[node], e = startL[node + 1];
        int i = s;
        for (; i + 4 <= e; i += 4) {
            const float2 p0 = packedL[i], p1 = packedL[i + 1];
            const float2 p2 = packedL[i + 2], p3 = packedL[i + 3];
            const float g0 = hl[(size_t)__float_as_int(p0.x) * 64 + lane];
            const float g1 = hl[(size_t)__float_as_int(p1.x) * 64 + lane];
            const float g2 = hl[(size_t)__float_as_int(p2.x) * 64 + lane];
            const float g3 = hl[(size_t)__float_as_int(p3.x) * 64 + lane];
            accL = fmaf(p0.y, g0, accL);
            accL = fmaf(p1.y, g1, accL);
            accL = fmaf(p2.y, g2, accL);
            accL = fmaf(p3.y, g3, accL);
        }
        for (; i < e; ++i) {
            const float2 p = packedL[i];
            accL = fmaf(p.y, hl[(size_t)__float_as_int(p.x) * 64 + lane], accL);
        }
    }
    {
        const int s = startH[node], e = startH[node + 1];
        int i = s;
        for (; i + 4 <= e; i += 4) {
            const float2 p0 = packedH[i], p1 = packedH[i + 1];
            const float2 p2 = packedH[i + 2], p3 = packedH[i + 3];
            const float g0 = hh[(size_t)__float_as_int(p0.x) * 64 + lane];
            const float g1 = hh[(size_t)__float_as_int(p1.x) * 64 + lane];
            const float g2 = hh[(size_t)__float_as_int(p2.x) * 64 + lane];
            const float g3 = hh[(size_t)__float_as_int(p3.x) * 64 + lane];
            accH = fmaf(p0.y, g0, accH);
            accH = fmaf(p1.y, g1, accH);
            accH = fmaf(p2.y, g2, accH);
            accH = fmaf(p3.y, g3, accH);
        }
        for (; i < e; ++i) {
            const float2 p = packedH[i];
            accH = fmaf(p.y, hh[(size_t)__float_as_int(p.x) * 64 + lane], accH);
        }
    }

    const size_t base = (size_t)node * 64 + lane;
    const float ol = fmaxf(accL, 0.f);
    const float oh = fmaxf(accH, 0.f);
    const float om = hm[base];

    float f0 = ol * aL[lane];
    float f1 = oh * aH[lane];
    float f2 = om * aM[lane];
#pragma unroll
    for (int msk = 1; msk < 64; msk <<= 1) {
        f0 += __shfl_xor(f0, msk, 64);
        f1 += __shfl_xor(f1, msk, 64);
        f2 += __shfl_xor(f2, msk, 64);
    }
    const float s0 = 1.f / (1.f + __expf(-f0));
    const float s1 = 1.f / (1.f + __expf(-f1));
    const float s2 = 1.f / (1.f + __expf(-f2));
    const float invT = 1.f / 3.f;
    const float l0 = (s0 * att3[0] + s1 * att3[3] + s2 * att3[6]) * invT;
    const float l1 = (s0 * att3[1] + s1 * att3[4] + s2 * att3[7]) * invT;
    const float l2 = (s0 * att3[2] + s1 * att3[5] + s2 * att3[8]) * invT;
    const float mx = fmaxf(l0, fmaxf(l1, l2));
    const float e0 = __expf(l0 - mx);
    const float e1 = __expf(l1 - mx);
    const float e2 = __expf(l2 - mx);
    const float inv = 1.f / (e0 + e1 + e2);
    out[base] = 3.f * inv * (e0 * ol + e1 * oh + e2 * om);
}

extern "C" void kernel_launch(void* const* d_in, const int* in_sizes, int n_in,
                              void* d_out, int out_size, void* d_ws, size_t ws_size,
                              hipStream_t stream)
{
    const float* x        = (const float*)d_in[0];
    const int*   row_low  = (const int*)  d_in[1];
    const int*   col_low  = (const int*)  d_in[2];
    const float* val_low  = (const float*)d_in[3];
    const int*   row_high = (const int*)  d_in[4];
    const int*   col_high = (const int*)  d_in[5];
    const float* val_high = (const float*)d_in[6];
    const float* W_low    = (const float*)d_in[7];
    const float* W_high   = (const float*)d_in[8];
    const float* W_mlp    = (const float*)d_in[9];
    const float* a_low    = (const float*)d_in[10];
    const float* a_high   = (const float*)d_in[11];
    const float* a_mlp    = (const float*)d_in[12];
    const float* att3     = (const float*)d_in[13];
    float* out = (float*)d_out;

    const int N = NNODE;
    const size_t NM = (size_t)N * 64;

    // workspace layout
    float*  hl      = (float*)d_ws;                  // N*64
    float*  hh      = hl + NM;                       // N*64
    float*  hm      = hh + NM;                       // N*64
    float2* packedL = (float2*)(hm + NM);            // E
    float2* packedH = packedL + NEDGE;               // E
    int*    cnt     = (int*)(packedH + NEDGE);       // 2N
    int*    startL  = cnt + 2 * N;                   // N+1
    int*    startH  = startL + (N + 1);              // N+1
    int*    cursor  = startH + (N + 1);              // 2N

    // zero the histogram counters
    hipMemsetAsync(cnt, 0, 2 * N * sizeof(int), stream);

    // CSR build
    hist_kernel<<<2048, 256, 0, stream>>>(row_low, row_high, cnt);
    scan_kernel<<<2, 1024, 0, stream>>>(cnt, startL, startH, cursor);
    scatter_kernel<<<2048, 256, 0, stream>>>(row_low, col_low, val_low,
                                             row_high, col_high, val_high,
                                             cursor, packedL, packedH);

    // dense projections
    dim3 g1((N + 63) / 64, 3);
    gemm3_kernel<<<g1, 64, 0, stream>>>(x, W_low, W_high, W_mlp, hl, hh, hm, N);

    // fused gather-SpMM + attention
    spmm_finalize_kernel<<<(N + 3) / 4, 256, 0, stream>>>(
        startL, startH, packedL, packedH, hl, hh, hm,
        a_low, a_high, a_mlp, att3, out);
}